// Round 10
// baseline (375.851 us; speedup 1.0000x reference)
//
#include <hip/hip_runtime.h>
#include <hip/hip_bf16.h>
#include <hip/hip_fp8.h>
#include <math.h>

#define N_NODES 50000
#define N_EDGES 1600000
#define NFEAT 512
#define NHID 128
#define NCLASS 40

#define NBUCKETS 196      // dst>>8 (r8: finer buckets doubled bin write-amp)
#define BUCKET_CAP 16384

// planar fp8 hidden tables: 2 planes x [N_NODES][64] = 3.2MB each -> each pass's
// gather working set fits a 4MB per-XCD L2 (6.4MB monolithic did not).
#define PLANE ((size_t)N_NODES * 64)

typedef __attribute__((ext_vector_type(8))) short bf16x8;
typedef __attribute__((ext_vector_type(4))) float f32x4;
typedef __attribute__((ext_vector_type(2))) float f32x2;

static __device__ __forceinline__ float asfloat_u32(unsigned int u) {
    union { unsigned int u; float f; } c;
    c.u = u;
    return c.f;
}
static __device__ __forceinline__ unsigned int asu32_f(float f) {
    union { float f; unsigned int u; } c;
    c.f = f;
    return c.u;
}
static __device__ __forceinline__ unsigned short f2bf(float f) {
    union { float f; unsigned int u; } c;
    c.f = f;
    unsigned int r = c.u + 0x7FFFu + ((c.u >> 16) & 1u);  // RTN-even
    return (unsigned short)(r >> 16);
}

// ---------- fp8 e4m3fn (OCP) helpers ----------
static __device__ __forceinline__ float fp8_to_f32_sw(unsigned int x) {
    float m = asfloat_u32((x & 0x7Fu) << 20) * 0x1p+120f;
    return asfloat_u32(asu32_f(m) | ((x & 0x80u) << 24));
}
static __device__ __forceinline__ void dq4(unsigned int u, float* f) {
#if __has_builtin(__builtin_amdgcn_cvt_pk_f32_fp8)
    f32x2 lo = __builtin_amdgcn_cvt_pk_f32_fp8(u, false);
    f32x2 hi = __builtin_amdgcn_cvt_pk_f32_fp8(u, true);
    f[0] = lo[0]; f[1] = lo[1]; f[2] = hi[0]; f[3] = hi[1];
#else
    f[0] = fp8_to_f32_sw(u & 0xFFu);
    f[1] = fp8_to_f32_sw((u >> 8) & 0xFFu);
    f[2] = fp8_to_f32_sw((u >> 16) & 0xFFu);
    f[3] = fp8_to_f32_sw((u >> 24) & 0xFFu);
#endif
}
static __device__ __forceinline__ unsigned char f2fp8(float f) {
#if __has_builtin(__builtin_amdgcn_cvt_pk_fp8_f32)
    int v = __builtin_amdgcn_cvt_pk_fp8_f32(f, f, 0, false);
    return (unsigned char)(v & 0xFF);
#else
    __hip_fp8_e4m3 h(f);
    return (unsigned char)h.__x;
#endif
}

// ---------------- prep: bucket cursors + weight transposes (W1, Wh, W2) ----------------
__global__ __launch_bounds__(256) void prep_kernel(const float* __restrict__ W1,
                                                   unsigned short* __restrict__ Wt1,
                                                   const float* __restrict__ Wh,
                                                   unsigned short* __restrict__ Wth,
                                                   const float* __restrict__ W2,
                                                   unsigned short* __restrict__ Wt2,
                                                   int* __restrict__ bucketCursor) {
    int idx = blockIdx.x * 256 + threadIdx.x;
    if (idx < NFEAT * NHID) {  // Wt1[n][k] = bf16(W1[k][n])
        int k = idx >> 7;
        int n = idx & 127;
        Wt1[(size_t)n * NFEAT + k] = f2bf(W1[idx]);
    } else if (idx < NFEAT * NHID + NHID * NHID) {
        int j = idx - NFEAT * NHID;
        int k = j >> 7;
        int n = j & 127;
        Wth[(size_t)n * NHID + k] = f2bf(Wh[j]);
    } else if (idx < NFEAT * NHID + NHID * NHID + 64 * NHID) {
        int j = idx - (NFEAT * NHID + NHID * NHID);
        int n = j & 63;
        int k = j >> 6;
        Wt2[(size_t)n * NHID + k] = (n < NCLASS) ? f2bf(W2[(size_t)k * NCLASS + n]) : 0;
    } else {
        int j = idx - (NFEAT * NHID + NHID * NHID + 64 * NHID);
        if (j < NBUCKETS) bucketCursor[j] = j * BUCKET_CAP;
    }
}

// ---------------- GEMM (64-row tile) body, N=128, BK=64, A-direct, 18KB LDS --------
// Best-measured structure (r5: 77.7us fused; r6 zero-LDS was worse; r1/r4
// prefetch/dbuf worse). fp8 output goes to the PLANAR table layout.
#define LDPB 72
#define GEMM_LDS_BYTES (128 * LDPB * 2)  // 18432 B

template <bool A_IS_BF16>
static __device__ __forceinline__ void gemm64_body(const void* __restrict__ Ap,
                                                   const unsigned short* __restrict__ Wt,
                                                   unsigned char* __restrict__ C8,
                                                   const int M, const int K,
                                                   char* smem, int bid) {
    unsigned short* Bs = (unsigned short*)smem;  // 128 x LDPB
    const int tid = threadIdx.x;
    const int wave = tid >> 6;
    const int lane = tid & 63;
    const int ln = lane & 15;
    const int quad = lane >> 4;
    const int row0 = bid * 64;

    const int arow = row0 + wave * 16 + ln;  // this lane's exclusive A row
    const bool aOk = arow < M;
    const unsigned short* Abf = (const unsigned short*)Ap + (size_t)arow * K + quad * 8;
    const float* Af = (const float*)Ap + (size_t)arow * K + quad * 8;

    const int bn = tid >> 1;        // B staging col(n) 0..127
    const int bk = (tid & 1) * 32;  // B staging k-offset (32 elems = 4x bf16x8)
    const unsigned short* Bg = Wt + (size_t)bn * K + bk;

    f32x4 acc[8];
#pragma unroll
    for (int t = 0; t < 8; ++t) acc[t] = (f32x4){0.f, 0.f, 0.f, 0.f};

    for (int kc = 0; kc < K; kc += 64) {
        bf16x8 qb0 = *(const bf16x8*)(Bg + kc);
        bf16x8 qb1 = *(const bf16x8*)(Bg + kc + 8);
        bf16x8 qb2 = *(const bf16x8*)(Bg + kc + 16);
        bf16x8 qb3 = *(const bf16x8*)(Bg + kc + 24);

        bf16x8 a0, a1;
        if (A_IS_BF16) {
            if (aOk) {
                a0 = *(const bf16x8*)(Abf + kc);
                a1 = *(const bf16x8*)(Abf + kc + 32);
            } else {
#pragma unroll
                for (int j = 0; j < 8; ++j) { a0[j] = 0; a1[j] = 0; }
            }
        } else {
            if (aOk) {
                float4 f0 = *(const float4*)(Af + kc);
                float4 f1 = *(const float4*)(Af + kc + 4);
                float4 f2 = *(const float4*)(Af + kc + 32);
                float4 f3 = *(const float4*)(Af + kc + 36);
                a0[0] = (short)f2bf(f0.x); a0[1] = (short)f2bf(f0.y);
                a0[2] = (short)f2bf(f0.z); a0[3] = (short)f2bf(f0.w);
                a0[4] = (short)f2bf(f1.x); a0[5] = (short)f2bf(f1.y);
                a0[6] = (short)f2bf(f1.z); a0[7] = (short)f2bf(f1.w);
                a1[0] = (short)f2bf(f2.x); a1[1] = (short)f2bf(f2.y);
                a1[2] = (short)f2bf(f2.z); a1[3] = (short)f2bf(f2.w);
                a1[4] = (short)f2bf(f3.x); a1[5] = (short)f2bf(f3.y);
                a1[6] = (short)f2bf(f3.z); a1[7] = (short)f2bf(f3.w);
            } else {
#pragma unroll
                for (int j = 0; j < 8; ++j) { a0[j] = 0; a1[j] = 0; }
            }
        }

        __syncthreads();  // previous iteration's B readers done
        *(bf16x8*)&Bs[bn * LDPB + bk] = qb0;
        *(bf16x8*)&Bs[bn * LDPB + bk + 8] = qb1;
        *(bf16x8*)&Bs[bn * LDPB + bk + 16] = qb2;
        *(bf16x8*)&Bs[bn * LDPB + bk + 24] = qb3;
        __syncthreads();

#pragma unroll
        for (int t = 0; t < 8; ++t) {
            bf16x8 b0 = *(const bf16x8*)&Bs[(t * 16 + ln) * LDPB + quad * 8];
            acc[t] = __builtin_amdgcn_mfma_f32_16x16x32_bf16(a0, b0, acc[t], 0, 0, 0);
        }
#pragma unroll
        for (int t = 0; t < 8; ++t) {
            bf16x8 b1 = *(const bf16x8*)&Bs[(t * 16 + ln) * LDPB + 32 + quad * 8];
            acc[t] = __builtin_amdgcn_mfma_f32_16x16x32_bf16(a1, b1, acc[t], 0, 0, 0);
        }
    }

    // planar fp8 epilogue: col c -> plane c>>6, offset row*64 + (c&63)
#pragma unroll
    for (int t = 0; t < 8; ++t) {
        int col = t * 16 + ln;
        unsigned char* Cp = C8 + (size_t)(col >> 6) * PLANE + (col & 63);
#pragma unroll
        for (int r = 0; r < 4; ++r) {
            int row = row0 + wave * 16 + quad * 4 + r;
            if (row < M) Cp[(size_t)row * 64] = f2fp8(acc[t][r]);
        }
    }
}

// ---------------- bin body: bucket edges by dst>>8 (scatter; ~2KB LDS) ----------------
static __device__ __forceinline__ void bin_body(const int* __restrict__ src,
                                                const int* __restrict__ dst,
                                                const float* __restrict__ w,
                                                int* __restrict__ bucketCursor,
                                                uint2* __restrict__ binned,
                                                int n, char* smem, int bid) {
    int* hist = (int*)smem;            // NBUCKETS
    int* cur = (int*)smem + NBUCKETS;  // NBUCKETS
    const int tid = threadIdx.x;
    const int base = bid * 4096;
    if (tid < NBUCKETS) hist[tid] = 0;
    __syncthreads();
#pragma unroll
    for (int r = 0; r < 16; ++r) {
        int e = base + r * 256 + tid;
        if (e < n) atomicAdd(&hist[dst[e] >> 8], 1);
    }
    __syncthreads();
    if (tid < NBUCKETS && hist[tid] > 0)
        cur[tid] = atomicAdd(&bucketCursor[tid], hist[tid]);
    __syncthreads();
#pragma unroll
    for (int r = 0; r < 16; ++r) {
        int e = base + r * 256 + tid;
        if (e < n) {
            int d = dst[e];
            int pos = atomicAdd(&cur[d >> 8], 1);
            uint2 rec;
            rec.x = (unsigned int)src[e] | ((unsigned int)(d & 255) << 16);
            rec.y = asu32_f(w[e]);
            binned[pos] = rec;
        }
    }
}

// ---------------- fused: GEMM1 (782 blocks) || bin (391 blocks) ----------------
#define GEMM1_BLOCKS 782
#define BIN_BLOCKS 391
__global__ __launch_bounds__(256) void fused_gemm1_bin(const float* __restrict__ x,
                                                       const unsigned short* __restrict__ Wt1,
                                                       unsigned char* __restrict__ tb,
                                                       const int* __restrict__ src,
                                                       const int* __restrict__ dst,
                                                       const float* __restrict__ w,
                                                       int* __restrict__ bucketCursor,
                                                       uint2* __restrict__ binned) {
    __shared__ char smem[GEMM_LDS_BYTES];
    if (blockIdx.x < GEMM1_BLOCKS) {
        gemm64_body<false>(x, Wt1, tb, N_NODES, NFEAT, smem, blockIdx.x);
    } else {
        bin_body(src, dst, w, bucketCursor, binned, N_EDGES, smem,
                 blockIdx.x - GEMM1_BLOCKS);
    }
}

// ---------------- GEMM layer 2: K=128, B fully LDS-staged, single barrier --------
#define LDP2 136
__global__ __launch_bounds__(256) void gemm64_l2(const unsigned short* __restrict__ A,
                                                 const unsigned short* __restrict__ Wt,
                                                 unsigned char* __restrict__ C) {
    __shared__ unsigned short Bs[128 * LDP2];
    const int tid = threadIdx.x;
    const int wave = tid >> 6;
    const int lane = tid & 63;
    const int ln = lane & 15;
    const int quad = lane >> 4;
    const int row0 = blockIdx.x * 64;
    const int arow = row0 + wave * 16 + ln;
    const bool aOk = arow < N_NODES;
    const unsigned short* Abf = A + (size_t)arow * 128 + quad * 8;

    bf16x8 a0, a1, a2, a3;
    if (aOk) {
        a0 = *(const bf16x8*)(Abf);
        a1 = *(const bf16x8*)(Abf + 32);
        a2 = *(const bf16x8*)(Abf + 64);
        a3 = *(const bf16x8*)(Abf + 96);
    } else {
#pragma unroll
        for (int j = 0; j < 8; ++j) { a0[j] = 0; a1[j] = 0; a2[j] = 0; a3[j] = 0; }
    }

#pragma unroll
    for (int i = 0; i < 8; ++i) {  // B: 128 rows x 128 = 2048 chunks of 8
        int q = tid + 256 * i;
        int r = q >> 4;
        int c = (q & 15) * 8;
        *(bf16x8*)&Bs[r * LDP2 + c] = *(const bf16x8*)(Wt + (size_t)r * 128 + c);
    }
    __syncthreads();

    f32x4 acc[8];
#pragma unroll
    for (int t = 0; t < 8; ++t) acc[t] = (f32x4){0.f, 0.f, 0.f, 0.f};

#pragma unroll
    for (int t = 0; t < 8; ++t) {
        bf16x8 b = *(const bf16x8*)&Bs[(t * 16 + ln) * LDP2 + quad * 8];
        acc[t] = __builtin_amdgcn_mfma_f32_16x16x32_bf16(a0, b, acc[t], 0, 0, 0);
    }
#pragma unroll
    for (int t = 0; t < 8; ++t) {
        bf16x8 b = *(const bf16x8*)&Bs[(t * 16 + ln) * LDP2 + 32 + quad * 8];
        acc[t] = __builtin_amdgcn_mfma_f32_16x16x32_bf16(a1, b, acc[t], 0, 0, 0);
    }
#pragma unroll
    for (int t = 0; t < 8; ++t) {
        bf16x8 b = *(const bf16x8*)&Bs[(t * 16 + ln) * LDP2 + 64 + quad * 8];
        acc[t] = __builtin_amdgcn_mfma_f32_16x16x32_bf16(a2, b, acc[t], 0, 0, 0);
    }
#pragma unroll
    for (int t = 0; t < 8; ++t) {
        bf16x8 b = *(const bf16x8*)&Bs[(t * 16 + ln) * LDP2 + 96 + quad * 8];
        acc[t] = __builtin_amdgcn_mfma_f32_16x16x32_bf16(a3, b, acc[t], 0, 0, 0);
    }

#pragma unroll
    for (int t = 0; t < 8; ++t) {
        int col = t * 16 + ln;
        unsigned char* Cp = C + (size_t)(col >> 6) * PLANE + (col & 63);
#pragma unroll
        for (int r = 0; r < 4; ++r) {
            int row = row0 + wave * 16 + quad * 4 + r;
            if (row < N_NODES) Cp[(size_t)row * 64] = f2fp8(acc[t][r]);
        }
    }
}

// ---------------- build_csr (inline bucket scan): 4B edge records ----------------
__global__ __launch_bounds__(1024) void build_csr(const uint2* __restrict__ binned,
                                                  const int* __restrict__ bucketCursor,
                                                  unsigned int* __restrict__ pairs,
                                                  int* __restrict__ row_ptr) {
    __shared__ int bs[256];
    __shared__ int hist[256];
    __shared__ int sc[256];
    __shared__ int cur[256];
    const int b = blockIdx.x;
    const int tid = threadIdx.x;

    if (tid < 256) bs[tid] = (tid < NBUCKETS) ? (bucketCursor[tid] - tid * BUCKET_CAP) : 0;
    if (tid < 256) hist[tid] = 0;
    __syncthreads();
    for (int off = 1; off < 256; off <<= 1) {
        int t = 0;
        if (tid < 256 && tid >= off) t = bs[tid - off];
        __syncthreads();
        if (tid < 256) bs[tid] += t;
        __syncthreads();
    }
    const int cnt = bucketCursor[b] - b * BUCKET_CAP;
    const int segStart = bs[b] - cnt;  // exclusive prefix at b
    if (b == NBUCKETS - 1 && tid == 0) row_ptr[N_NODES] = bs[NBUCKETS - 1];
    const uint2* seg = binned + (size_t)b * BUCKET_CAP;

    for (int i = tid; i < cnt; i += 1024)
        atomicAdd(&hist[seg[i].x >> 16], 1);
    __syncthreads();
    if (tid < 256) {
        int v = hist[tid];
        sc[tid] = v;
    }
    __syncthreads();
    for (int off = 1; off < 256; off <<= 1) {
        int t = 0;
        if (tid < 256 && tid >= off) t = sc[tid - off];
        __syncthreads();
        if (tid < 256) sc[tid] += t;
        __syncthreads();
    }
    if (tid < 256) {
        int excl = sc[tid] - hist[tid];
        int node = b * 256 + tid;
        if (node < N_NODES) row_ptr[node] = segStart + excl;
        cur[tid] = segStart + excl;
    }
    __syncthreads();
    for (int i = tid; i < cnt; i += 1024) {
        uint2 p = seg[i];
        int pos = atomicAdd(&cur[p.x >> 16], 1);
        pairs[pos] = (p.x & 0xFFFFu) | ((unsigned int)f2bf(asfloat_u32(p.y)) << 16);
    }
}

// ---------------- GEMM, N=64(->40 valid), K=128, MFMA, fully-staged, fp8 out --------
__global__ __launch_bounds__(256) void gemm_n64(const unsigned short* __restrict__ A,
                                                const unsigned short* __restrict__ Wt2,
                                                unsigned char* __restrict__ C, int M) {
    __shared__ unsigned short As[64 * LDP2];
    __shared__ unsigned short Bs2[64 * LDP2];
    const int tid = threadIdx.x;
    const int wave = tid >> 6;
    const int lane = tid & 63;
    const int ln = lane & 15;
    const int quad = lane >> 4;
    const int row0 = blockIdx.x * 64;

#pragma unroll
    for (int i = 0; i < 4; ++i) {  // A: 64 rows x 128 = 1024 chunks of 8
        int q = tid + 256 * i;
        int r = q >> 4;
        int c = (q & 15) * 8;
        bf16x8 v;
        if (row0 + r < M) {
            v = *(const bf16x8*)(A + (size_t)(row0 + r) * 128 + c);
        } else {
#pragma unroll
            for (int j = 0; j < 8; ++j) v[j] = 0;
        }
        *(bf16x8*)&As[r * LDP2 + c] = v;
    }
#pragma unroll
    for (int i = 0; i < 4; ++i) {  // B: 64 rows x 128 = 1024 chunks of 8
        int q = tid + 256 * i;
        int r = q >> 4;
        int c = (q & 15) * 8;
        *(bf16x8*)&Bs2[r * LDP2 + c] = *(const bf16x8*)(Wt2 + (size_t)r * 128 + c);
    }
    __syncthreads();

    f32x4 acc[4];
#pragma unroll
    for (int t = 0; t < 4; ++t) acc[t] = (f32x4){0.f, 0.f, 0.f, 0.f};

#pragma unroll
    for (int kc = 0; kc < 128; kc += 32) {
        bf16x8 a = *(const bf16x8*)&As[(wave * 16 + ln) * LDP2 + kc + quad * 8];
#pragma unroll
        for (int t = 0; t < 4; ++t) {
            bf16x8 b = *(const bf16x8*)&Bs2[(t * 16 + ln) * LDP2 + kc + quad * 8];
            acc[t] = __builtin_amdgcn_mfma_f32_16x16x32_bf16(a, b, acc[t], 0, 0, 0);
        }
    }

#pragma unroll
    for (int t = 0; t < 4; ++t) {
#pragma unroll
        for (int r = 0; r < 4; ++r) {
            int row = row0 + wave * 16 + quad * 4 + r;
            if (row < M) C[(size_t)row * 64 + t * 16 + ln] = f2fp8(acc[t][r]);
        }
    }
}

// ---------------- SpMM two-pass planar (fp8 64B rows, L2-resident) + bias + ReLU ----
// Per half h: table plane (3.2MB) fits per-XCD L2. EIGHT 8-lane groups; group g
// gathers edge e+4i*8+g... -> 8 edges per load instr, unroll 4 -> 32 in flight.
// Butterfly over groups (xor 8,16,32); group 0 writes 16B bf16 per lane.
__global__ __launch_bounds__(256) void spmm_bias_relu_fp8(const unsigned char* __restrict__ t,
                                                          const int* __restrict__ row_ptr,
                                                          const unsigned int* __restrict__ pairs,
                                                          const float* __restrict__ bias,
                                                          unsigned short* __restrict__ out) {
    const int node = blockIdx.x * 4 + (threadIdx.x >> 6);
    const int lane = threadIdx.x & 63;
    const int g = lane >> 3;        // group 0..7
    const int fl = (lane & 7) * 8;  // feature base within half (8 fp8 = 8B)
    const int e0 = row_ptr[node];
    const int e1 = row_ptr[node + 1];

#pragma unroll
    for (int h = 0; h < 2; ++h) {
        const unsigned char* tbl = t + (size_t)h * PLANE;
        float acc8[8];
#pragma unroll
        for (int j = 0; j < 8; ++j) acc8[j] = 0.f;

        int e = e0;
        for (; e + 32 <= e1; e += 32) {
            unsigned int p[4];
            uint2 v[4];
#pragma unroll
            for (int i = 0; i < 4; ++i) p[i] = pairs[e + 8 * i + g];
#pragma unroll
            for (int i = 0; i < 4; ++i)
                v[i] = *(const uint2*)(tbl + (size_t)(p[i] & 0xFFFFu) * 64 + fl);
#pragma unroll
            for (int i = 0; i < 4; ++i) {
                float w = asfloat_u32(p[i] & 0xFFFF0000u);
                float f[8];
                dq4(v[i].x, f);
                dq4(v[i].y, f + 4);
#pragma unroll
                for (int j = 0; j < 8; ++j) acc8[j] += w * f[j];
            }
        }
        for (; e + 8 <= e1; e += 8) {
            unsigned int p = pairs[e + g];
            uint2 v = *(const uint2*)(tbl + (size_t)(p & 0xFFFFu) * 64 + fl);
            float w = asfloat_u32(p & 0xFFFF0000u);
            float f[8];
            dq4(v.x, f);
            dq4(v.y, f + 4);
#pragma unroll
            for (int j = 0; j < 8; ++j) acc8[j] += w * f[j];
        }
        if (g < e1 - e) {  // remainder 0..7 edges, one per group
            unsigned int p = pairs[e + g];
            uint2 v = *(const uint2*)(tbl + (size_t)(p & 0xFFFFu) * 64 + fl);
            float w = asfloat_u32(p & 0xFFFF0000u);
            float f[8];
            dq4(v.x, f);
            dq4(v.y, f + 4);
#pragma unroll
            for (int j = 0; j < 8; ++j) acc8[j] += w * f[j];
        }
        // lanes l, l^8, l^16, ..., l^56 own the same 8 features
#pragma unroll
        for (int j = 0; j < 8; ++j) {
            acc8[j] += __shfl_xor(acc8[j], 8);
            acc8[j] += __shfl_xor(acc8[j], 16);
            acc8[j] += __shfl_xor(acc8[j], 32);
        }
        if (g == 0) {
            const int fb = h * 64 + fl;
            float4 b0 = *(const float4*)&bias[fb];
            float4 b1 = *(const float4*)&bias[fb + 4];
            acc8[0] = fmaxf(acc8[0] + b0.x, 0.f);
            acc8[1] = fmaxf(acc8[1] + b0.y, 0.f);
            acc8[2] = fmaxf(acc8[2] + b0.z, 0.f);
            acc8[3] = fmaxf(acc8[3] + b0.w, 0.f);
            acc8[4] = fmaxf(acc8[4] + b1.x, 0.f);
            acc8[5] = fmaxf(acc8[5] + b1.y, 0.f);
            acc8[6] = fmaxf(acc8[6] + b1.z, 0.f);
            acc8[7] = fmaxf(acc8[7] + b1.w, 0.f);
            uint4 o;
            o.x = ((unsigned int)f2bf(acc8[0])) | (((unsigned int)f2bf(acc8[1])) << 16);
            o.y = ((unsigned int)f2bf(acc8[2])) | (((unsigned int)f2bf(acc8[3])) << 16);
            o.z = ((unsigned int)f2bf(acc8[4])) | (((unsigned int)f2bf(acc8[5])) << 16);
            o.w = ((unsigned int)f2bf(acc8[6])) | (((unsigned int)f2bf(acc8[7])) << 16);
            *(uint4*)(out + (size_t)node * 128 + fb) = o;
        }
    }
}

// ---------------- SpMM feat=64pad (fp8 rows, 64B) + bias + log_softmax ----------------
__global__ __launch_bounds__(256) void spmm_logsoftmax(const unsigned char* __restrict__ t,
                                                       const int* __restrict__ row_ptr,
                                                       const unsigned int* __restrict__ pairs,
                                                       const float* __restrict__ bias,
                                                       float* __restrict__ out) {
    const int node = blockIdx.x * 4 + (threadIdx.x >> 6);
    const int lane = threadIdx.x & 63;
    const int g = lane >> 4;
    const int fe = (lane & 15) * 4;  // class base (4 fp8 = 4B)
    const int e0 = row_ptr[node];
    const int e1 = row_ptr[node + 1];
    float a0 = 0.f, a1 = 0.f, a2 = 0.f, a3 = 0.f;
    int e = e0;
    for (; e + 32 <= e1; e += 32) {
        unsigned int p[8];
        unsigned int v[8];
#pragma unroll
        for (int i = 0; i < 8; ++i) p[i] = pairs[e + 4 * i + g];
#pragma unroll
        for (int i = 0; i < 8; ++i)
            v[i] = *(const unsigned int*)(t + (size_t)(p[i] & 0xFFFFu) * 64 + fe);
#pragma unroll
        for (int i = 0; i < 8; ++i) {
            float w = asfloat_u32(p[i] & 0xFFFF0000u);
            float f[4];
            dq4(v[i], f);
            a0 += w * f[0];
            a1 += w * f[1];
            a2 += w * f[2];
            a3 += w * f[3];
        }
    }
    for (; e + 4 <= e1; e += 4) {
        unsigned int p = pairs[e + g];
        unsigned int v = *(const unsigned int*)(t + (size_t)(p & 0xFFFFu) * 64 + fe);
        float w = asfloat_u32(p & 0xFFFF0000u);
        float f[4];
        dq4(v, f);
        a0 += w * f[0]; a1 += w * f[1]; a2 += w * f[2]; a3 += w * f[3];
    }
    if (g < e1 - e) {
        unsigned int p = pairs[e + g];
        unsigned int v = *(const unsigned int*)(t + (size_t)(p & 0xFFFFu) * 64 + fe);
        float w = asfloat_u32(p & 0xFFFF0000u);
        float f[4];
        dq4(v, f);
        a0 += w * f[0]; a1 += w * f[1]; a2 += w * f[2]; a3 += w * f[3];
    }
    a0 += __shfl_xor(a0, 16); a0 += __shfl_xor(a0, 32);
    a1 += __shfl_xor(a1, 16); a1 += __shfl_xor(a1, 32);
    a2 += __shfl_xor(a2, 16); a2 += __shfl_xor(a2, 32);
    a3 += __shfl_xor(a3, 16); a3 += __shfl_xor(a3, 32);

    const bool valid = (lane & 15) < 10;  // classes fe..fe+3 < 40
    float l0 = -INFINITY, l1 = -INFINITY, l2 = -INFINITY, l3 = -INFINITY;
    if (valid) {
        float4 b = *(const float4*)&bias[fe];
        l0 = a0 + b.x; l1 = a1 + b.y; l2 = a2 + b.z; l3 = a3 + b.w;
    }
    float m = fmaxf(fmaxf(l0, l1), fmaxf(l2, l3));
#pragma unroll
    for (int off = 8; off; off >>= 1) m = fmaxf(m, __shfl_xor(m, off));
    float s = valid ? (__expf(l0 - m) + __expf(l1 - m) + __expf(l2 - m) + __expf(l3 - m)) : 0.f;
#pragma unroll
    for (int off = 8; off; off >>= 1) s += __shfl_xor(s, off);
    if (valid && g == 0) {
        float ls = __logf(s);
        float4 o;
        o.x = l0 - m - ls; o.y = l1 - m - ls; o.z = l2 - m - ls; o.w = l3 - m - ls;
        *(float4*)&out[(size_t)node * NCLASS + fe] = o;
    }
}

// ---------------- launch ----------------

extern "C" void kernel_launch(void* const* d_in, const int* in_sizes, int n_in,
                              void* d_out, int out_size, void* d_ws, size_t ws_size,
                              hipStream_t stream) {
    const float* x = (const float*)d_in[0];
    const int* edge_src = (const int*)d_in[1];
    const int* edge_dst = (const int*)d_in[2];
    const float* edge_weight = (const float*)d_in[3];
    const float* W1 = (const float*)d_in[4];
    const float* b1 = (const float*)d_in[5];
    const float* Wh = (const float*)d_in[6];
    const float* bh = (const float*)d_in[7];
    const float* W2 = (const float*)d_in[8];
    const float* b2 = (const float*)d_in[9];
    float* out = (float*)d_out;

    size_t off = 0;
    auto carve = [&](size_t bytes) {
        void* p = (char*)d_ws + off;
        off += (bytes + 511) & ~(size_t)511;
        return p;
    };
    unsigned char* tb = (unsigned char*)carve((size_t)N_NODES * 128);   // 2 planar fp8 tables
    unsigned short* hb = (unsigned short*)carve((size_t)N_NODES * 128 * 2);
    unsigned char* t3 = (unsigned char*)carve((size_t)N_NODES * 64);    // fp8 logits table
    unsigned short* Wt1 = (unsigned short*)carve((size_t)NFEAT * NHID * 2);
    unsigned short* Wth = (unsigned short*)carve((size_t)NHID * NHID * 2);
    unsigned short* Wt2 = (unsigned short*)carve((size_t)64 * NHID * 2);
    int* row_ptr = (int*)carve((size_t)(N_NODES + 4) * 4);
    int* bucketCursor = (int*)carve((size_t)NBUCKETS * 4);
    uint2* binned = (uint2*)carve((size_t)NBUCKETS * BUCKET_CAP * 8);
    unsigned int* pairs = (unsigned int*)carve((size_t)N_EDGES * 4);
    (void)ws_size; (void)n_in; (void)in_sizes; (void)out_size;

    const int prepBlocks =
        (NFEAT * NHID + NHID * NHID + 64 * NHID + NBUCKETS + 255) / 256;  // 353
    const int spmmBlocks = N_NODES / 4;            // 12500
    const int gemmBlocks = (N_NODES + 63) / 64;    // 782

    // prep (weights + cursors)
    prep_kernel<<<prepBlocks, 256, 0, stream>>>(W1, Wt1, Wh, Wth, W2, Wt2, bucketCursor);

    // GEMM1 || bin (r5-proven fusion)
    fused_gemm1_bin<<<GEMM1_BLOCKS + BIN_BLOCKS, 256, 0, stream>>>(
        x, Wt1, tb, edge_src, edge_dst, edge_weight, bucketCursor, binned);

    // CSR finalize (inline bucket scan)
    build_csr<<<NBUCKETS, 1024, 0, stream>>>(binned, bucketCursor, pairs, row_ptr);

    // Layer 1 aggregate (two-pass L2-resident planar gather)
    spmm_bias_relu_fp8<<<spmmBlocks, 256, 0, stream>>>(tb, row_ptr, pairs, b1, hb);

    // Layer 2 (single-barrier fully-staged B, planar fp8 out)
    gemm64_l2<<<gemmBlocks, 256, 0, stream>>>(hb, Wth, tb);
    spmm_bias_relu_fp8<<<spmmBlocks, 256, 0, stream>>>(tb, row_ptr, pairs, bh, hb);

    // Layer 3 (MFMA, fully-staged tiles, fp8 64B logits table)
    gemm_n64<<<gemmBlocks, 256, 0, stream>>>(hb, Wt2, t3, N_NODES);
    spmm_logsoftmax<<<spmmBlocks, 256, 0, stream>>>(t3, row_ptr, pairs, b2, out);
}

// Round 11
// 355.171 us; speedup vs baseline: 1.0582x; 1.0582x over previous
//
#include <hip/hip_runtime.h>
#include <hip/hip_bf16.h>
#include <hip/hip_fp8.h>
#include <math.h>

#define N_NODES 50000
#define N_EDGES 1600000
#define NFEAT 512
#define NHID 128
#define NCLASS 40

// r8 lesson: dst>>6 (782 buckets) doubled bin write-amplification (25->50MB)
// and csr gained ~nothing -> back to the proven dst>>8 / 196-bucket config.
#define NBUCKETS 196
#define BUCKET_CAP 16384  // avg fill ~8163 -> huge margin

typedef __attribute__((ext_vector_type(8))) short bf16x8;
typedef __attribute__((ext_vector_type(4))) float f32x4;
typedef __attribute__((ext_vector_type(2))) float f32x2;

static __device__ __forceinline__ float asfloat_u32(unsigned int u) {
    union { unsigned int u; float f; } c;
    c.u = u;
    return c.f;
}
static __device__ __forceinline__ unsigned int asu32_f(float f) {
    union { float f; unsigned int u; } c;
    c.f = f;
    return c.u;
}
static __device__ __forceinline__ unsigned short f2bf(float f) {
    union { float f; unsigned int u; } c;
    c.f = f;
    unsigned int r = c.u + 0x7FFFu + ((c.u >> 16) & 1u);  // RTN-even
    return (unsigned short)(r >> 16);
}

// ---------- fp8 e4m3fn (OCP) helpers ----------
static __device__ __forceinline__ float fp8_to_f32_sw(unsigned int x) {
    float m = asfloat_u32((x & 0x7Fu) << 20) * 0x1p+120f;
    return asfloat_u32(asu32_f(m) | ((x & 0x80u) << 24));
}
static __device__ __forceinline__ void dq4(unsigned int u, float* f) {
#if __has_builtin(__builtin_amdgcn_cvt_pk_f32_fp8)
    f32x2 lo = __builtin_amdgcn_cvt_pk_f32_fp8(u, false);
    f32x2 hi = __builtin_amdgcn_cvt_pk_f32_fp8(u, true);
    f[0] = lo[0]; f[1] = lo[1]; f[2] = hi[0]; f[3] = hi[1];
#else
    f[0] = fp8_to_f32_sw(u & 0xFFu);
    f[1] = fp8_to_f32_sw((u >> 8) & 0xFFu);
    f[2] = fp8_to_f32_sw((u >> 16) & 0xFFu);
    f[3] = fp8_to_f32_sw((u >> 24) & 0xFFu);
#endif
}
static __device__ __forceinline__ unsigned char f2fp8(float f) {
#if __has_builtin(__builtin_amdgcn_cvt_pk_fp8_f32)
    int v = __builtin_amdgcn_cvt_pk_fp8_f32(f, f, 0, false);
    return (unsigned char)(v & 0xFF);
#else
    __hip_fp8_e4m3 h(f);
    return (unsigned char)h.__x;
#endif
}

// ---------------- prep: bucket cursors + weight transposes (W1, Wh, W2) ----------------
__global__ __launch_bounds__(256) void prep_kernel(const float* __restrict__ W1,
                                                   unsigned short* __restrict__ Wt1,
                                                   const float* __restrict__ Wh,
                                                   unsigned short* __restrict__ Wth,
                                                   const float* __restrict__ W2,
                                                   unsigned short* __restrict__ Wt2,
                                                   int* __restrict__ bucketCursor) {
    int idx = blockIdx.x * 256 + threadIdx.x;
    if (idx < NFEAT * NHID) {  // Wt1[n][k] = bf16(W1[k][n])
        int k = idx >> 7;
        int n = idx & 127;
        Wt1[(size_t)n * NFEAT + k] = f2bf(W1[idx]);
    } else if (idx < NFEAT * NHID + NHID * NHID) {
        int j = idx - NFEAT * NHID;
        int k = j >> 7;
        int n = j & 127;
        Wth[(size_t)n * NHID + k] = f2bf(Wh[j]);
    } else if (idx < NFEAT * NHID + NHID * NHID + 64 * NHID) {
        int j = idx - (NFEAT * NHID + NHID * NHID);
        int n = j & 63;
        int k = j >> 6;
        Wt2[(size_t)n * NHID + k] = (n < NCLASS) ? f2bf(W2[(size_t)k * NCLASS + n]) : 0;
    } else {
        int j = idx - (NFEAT * NHID + NHID * NHID + 64 * NHID);
        if (j < NBUCKETS) bucketCursor[j] = j * BUCKET_CAP;
    }
}

// ---------------- GEMM (64-row tile) body, N=128, BK=64, A-direct, 18KB LDS --------
// Best-measured structure (r5: 77.7us fused; r6 zero-LDS variant was WORSE).
#define LDPB 72
#define GEMM_LDS_BYTES (128 * LDPB * 2)  // 18432 B

template <bool A_IS_BF16, bool OUT_FP8>
static __device__ __forceinline__ void gemm64_body(const void* __restrict__ Ap,
                                                   const unsigned short* __restrict__ Wt,
                                                   void* __restrict__ Cv,
                                                   const int M, const int K,
                                                   char* smem, int bid) {
    unsigned short* Bs = (unsigned short*)smem;  // 128 x LDPB
    const int tid = threadIdx.x;
    const int wave = tid >> 6;
    const int lane = tid & 63;
    const int ln = lane & 15;
    const int quad = lane >> 4;
    const int row0 = bid * 64;

    const int arow = row0 + wave * 16 + ln;  // this lane's exclusive A row
    const bool aOk = arow < M;
    const unsigned short* Abf = (const unsigned short*)Ap + (size_t)arow * K + quad * 8;
    const float* Af = (const float*)Ap + (size_t)arow * K + quad * 8;

    const int bn = tid >> 1;        // B staging col(n) 0..127
    const int bk = (tid & 1) * 32;  // B staging k-offset (32 elems = 4x bf16x8)
    const unsigned short* Bg = Wt + (size_t)bn * K + bk;

    f32x4 acc[8];
#pragma unroll
    for (int t = 0; t < 8; ++t) acc[t] = (f32x4){0.f, 0.f, 0.f, 0.f};

    for (int kc = 0; kc < K; kc += 64) {
        bf16x8 qb0 = *(const bf16x8*)(Bg + kc);
        bf16x8 qb1 = *(const bf16x8*)(Bg + kc + 8);
        bf16x8 qb2 = *(const bf16x8*)(Bg + kc + 16);
        bf16x8 qb3 = *(const bf16x8*)(Bg + kc + 24);

        bf16x8 a0, a1;
        if (A_IS_BF16) {
            if (aOk) {
                a0 = *(const bf16x8*)(Abf + kc);
                a1 = *(const bf16x8*)(Abf + kc + 32);
            } else {
#pragma unroll
                for (int j = 0; j < 8; ++j) { a0[j] = 0; a1[j] = 0; }
            }
        } else {
            if (aOk) {
                float4 f0 = *(const float4*)(Af + kc);
                float4 f1 = *(const float4*)(Af + kc + 4);
                float4 f2 = *(const float4*)(Af + kc + 32);
                float4 f3 = *(const float4*)(Af + kc + 36);
                a0[0] = (short)f2bf(f0.x); a0[1] = (short)f2bf(f0.y);
                a0[2] = (short)f2bf(f0.z); a0[3] = (short)f2bf(f0.w);
                a0[4] = (short)f2bf(f1.x); a0[5] = (short)f2bf(f1.y);
                a0[6] = (short)f2bf(f1.z); a0[7] = (short)f2bf(f1.w);
                a1[0] = (short)f2bf(f2.x); a1[1] = (short)f2bf(f2.y);
                a1[2] = (short)f2bf(f2.z); a1[3] = (short)f2bf(f2.w);
                a1[4] = (short)f2bf(f3.x); a1[5] = (short)f2bf(f3.y);
                a1[6] = (short)f2bf(f3.z); a1[7] = (short)f2bf(f3.w);
            } else {
#pragma unroll
                for (int j = 0; j < 8; ++j) { a0[j] = 0; a1[j] = 0; }
            }
        }

        __syncthreads();  // previous iteration's B readers done
        *(bf16x8*)&Bs[bn * LDPB + bk] = qb0;
        *(bf16x8*)&Bs[bn * LDPB + bk + 8] = qb1;
        *(bf16x8*)&Bs[bn * LDPB + bk + 16] = qb2;
        *(bf16x8*)&Bs[bn * LDPB + bk + 24] = qb3;
        __syncthreads();

#pragma unroll
        for (int t = 0; t < 8; ++t) {
            bf16x8 b0 = *(const bf16x8*)&Bs[(t * 16 + ln) * LDPB + quad * 8];
            acc[t] = __builtin_amdgcn_mfma_f32_16x16x32_bf16(a0, b0, acc[t], 0, 0, 0);
        }
#pragma unroll
        for (int t = 0; t < 8; ++t) {
            bf16x8 b1 = *(const bf16x8*)&Bs[(t * 16 + ln) * LDPB + 32 + quad * 8];
            acc[t] = __builtin_amdgcn_mfma_f32_16x16x32_bf16(a1, b1, acc[t], 0, 0, 0);
        }
    }

    if (OUT_FP8) {
        unsigned char* C8 = (unsigned char*)Cv;
#pragma unroll
        for (int t = 0; t < 8; ++t) {
#pragma unroll
            for (int r = 0; r < 4; ++r) {
                int row = row0 + wave * 16 + quad * 4 + r;
                if (row < M) C8[(size_t)row * 128 + t * 16 + ln] = f2fp8(acc[t][r]);
            }
        }
    } else {
        unsigned short* C = (unsigned short*)Cv;
#pragma unroll
        for (int t = 0; t < 8; ++t) {
#pragma unroll
            for (int r = 0; r < 4; ++r) {
                int row = row0 + wave * 16 + quad * 4 + r;
                if (row < M) C[(size_t)row * 128 + t * 16 + ln] = f2bf(acc[t][r]);
            }
        }
    }
}

// ---------------- bin body: bucket edges by dst>>8 (scatter; ~2KB LDS) ----------------
// Record: x = src | (dstLow8)<<16 ; y = fp32 weight bits.
static __device__ __forceinline__ void bin_body(const int* __restrict__ src,
                                                const int* __restrict__ dst,
                                                const float* __restrict__ w,
                                                int* __restrict__ bucketCursor,
                                                uint2* __restrict__ binned,
                                                int n, char* smem, int bid) {
    int* hist = (int*)smem;            // NBUCKETS
    int* cur = (int*)smem + NBUCKETS;  // NBUCKETS
    const int tid = threadIdx.x;
    const int base = bid * 4096;
    if (tid < NBUCKETS) hist[tid] = 0;
    __syncthreads();
#pragma unroll
    for (int r = 0; r < 16; ++r) {
        int e = base + r * 256 + tid;
        if (e < n) atomicAdd(&hist[dst[e] >> 8], 1);
    }
    __syncthreads();
    if (tid < NBUCKETS && hist[tid] > 0)
        cur[tid] = atomicAdd(&bucketCursor[tid], hist[tid]);
    __syncthreads();
#pragma unroll
    for (int r = 0; r < 16; ++r) {
        int e = base + r * 256 + tid;
        if (e < n) {
            int d = dst[e];
            int pos = atomicAdd(&cur[d >> 8], 1);
            uint2 rec;
            rec.x = (unsigned int)src[e] | ((unsigned int)(d & 255) << 16);
            rec.y = asu32_f(w[e]);
            binned[pos] = rec;
        }
    }
}

// ---------------- fused: GEMM1 (782 blocks) || bin (391 blocks) ----------------
#define GEMM1_BLOCKS 782
#define BIN_BLOCKS 391
__global__ __launch_bounds__(256) void fused_gemm1_bin(const float* __restrict__ x,
                                                       const unsigned short* __restrict__ Wt1,
                                                       unsigned char* __restrict__ tb,
                                                       const int* __restrict__ src,
                                                       const int* __restrict__ dst,
                                                       const float* __restrict__ w,
                                                       int* __restrict__ bucketCursor,
                                                       uint2* __restrict__ binned) {
    __shared__ char smem[GEMM_LDS_BYTES];
    if (blockIdx.x < GEMM1_BLOCKS) {
        gemm64_body<false, true>(x, Wt1, tb, N_NODES, NFEAT, smem, blockIdx.x);
    } else {
        bin_body(src, dst, w, bucketCursor, binned, N_EDGES, smem,
                 blockIdx.x - GEMM1_BLOCKS);
    }
}

// ---------------- GEMM layer 2: K=128 -> B fully LDS-staged, SINGLE barrier --------
// B (Wth, 128x128 bf16 = 32KB) fits LDS once. A issued to registers BEFORE the
// staging barrier (per-lane-exclusive rows). Zero per-k-step barriers, 32 MFMAs.
// 34.8KB LDS -> 4 blocks/CU >= grid's 782/256 = 3.05 resident need.
#define LDP2 136
__global__ __launch_bounds__(256) void gemm64_l2(const unsigned short* __restrict__ A,
                                                 const unsigned short* __restrict__ Wt,
                                                 unsigned char* __restrict__ C) {
    __shared__ unsigned short Bs[128 * LDP2];
    const int tid = threadIdx.x;
    const int wave = tid >> 6;
    const int lane = tid & 63;
    const int ln = lane & 15;
    const int quad = lane >> 4;
    const int row0 = blockIdx.x * 64;
    const int arow = row0 + wave * 16 + ln;
    const bool aOk = arow < N_NODES;
    const unsigned short* Abf = A + (size_t)arow * 128 + quad * 8;

    // issue A loads early (independent of B staging)
    bf16x8 a0, a1, a2, a3;
    if (aOk) {
        a0 = *(const bf16x8*)(Abf);
        a1 = *(const bf16x8*)(Abf + 32);
        a2 = *(const bf16x8*)(Abf + 64);
        a3 = *(const bf16x8*)(Abf + 96);
    } else {
#pragma unroll
        for (int j = 0; j < 8; ++j) { a0[j] = 0; a1[j] = 0; a2[j] = 0; a3[j] = 0; }
    }

#pragma unroll
    for (int i = 0; i < 8; ++i) {  // B: 128 rows x 128 = 2048 chunks of 8
        int q = tid + 256 * i;
        int r = q >> 4;
        int c = (q & 15) * 8;
        *(bf16x8*)&Bs[r * LDP2 + c] = *(const bf16x8*)(Wt + (size_t)r * 128 + c);
    }
    __syncthreads();

    f32x4 acc[8];
#pragma unroll
    for (int t = 0; t < 8; ++t) acc[t] = (f32x4){0.f, 0.f, 0.f, 0.f};

#pragma unroll
    for (int t = 0; t < 8; ++t) {
        bf16x8 b = *(const bf16x8*)&Bs[(t * 16 + ln) * LDP2 + quad * 8];
        acc[t] = __builtin_amdgcn_mfma_f32_16x16x32_bf16(a0, b, acc[t], 0, 0, 0);
    }
#pragma unroll
    for (int t = 0; t < 8; ++t) {
        bf16x8 b = *(const bf16x8*)&Bs[(t * 16 + ln) * LDP2 + 32 + quad * 8];
        acc[t] = __builtin_amdgcn_mfma_f32_16x16x32_bf16(a1, b, acc[t], 0, 0, 0);
    }
#pragma unroll
    for (int t = 0; t < 8; ++t) {
        bf16x8 b = *(const bf16x8*)&Bs[(t * 16 + ln) * LDP2 + 64 + quad * 8];
        acc[t] = __builtin_amdgcn_mfma_f32_16x16x32_bf16(a2, b, acc[t], 0, 0, 0);
    }
#pragma unroll
    for (int t = 0; t < 8; ++t) {
        bf16x8 b = *(const bf16x8*)&Bs[(t * 16 + ln) * LDP2 + 96 + quad * 8];
        acc[t] = __builtin_amdgcn_mfma_f32_16x16x32_bf16(a3, b, acc[t], 0, 0, 0);
    }

#pragma unroll
    for (int t = 0; t < 8; ++t) {
#pragma unroll
        for (int r = 0; r < 4; ++r) {
            int row = row0 + wave * 16 + quad * 4 + r;
            if (row < N_NODES) C[(size_t)row * 128 + t * 16 + ln] = f2fp8(acc[t][r]);
        }
    }
}

// ---------------- build_csr (inline bucket scan): 4B edge records ----------------
__global__ __launch_bounds__(1024) void build_csr(const uint2* __restrict__ binned,
                                                  const int* __restrict__ bucketCursor,
                                                  unsigned int* __restrict__ pairs,
                                                  int* __restrict__ row_ptr) {
    __shared__ int bs[256];
    __shared__ int hist[256];
    __shared__ int sc[256];
    __shared__ int cur[256];
    const int b = blockIdx.x;
    const int tid = threadIdx.x;

    if (tid < 256) bs[tid] = (tid < NBUCKETS) ? (bucketCursor[tid] - tid * BUCKET_CAP) : 0;
    if (tid < 256) hist[tid] = 0;
    __syncthreads();
    for (int off = 1; off < 256; off <<= 1) {
        int t = 0;
        if (tid < 256 && tid >= off) t = bs[tid - off];
        __syncthreads();
        if (tid < 256) bs[tid] += t;
        __syncthreads();
    }
    const int cnt = bucketCursor[b] - b * BUCKET_CAP;
    const int segStart = bs[b] - cnt;  // exclusive prefix at b
    if (b == NBUCKETS - 1 && tid == 0) row_ptr[N_NODES] = bs[NBUCKETS - 1];
    const uint2* seg = binned + (size_t)b * BUCKET_CAP;

    for (int i = tid; i < cnt; i += 1024)
        atomicAdd(&hist[seg[i].x >> 16], 1);
    __syncthreads();
    if (tid < 256) {
        int v = hist[tid];
        sc[tid] = v;
    }
    __syncthreads();
    for (int off = 1; off < 256; off <<= 1) {
        int t = 0;
        if (tid < 256 && tid >= off) t = sc[tid - off];
        __syncthreads();
        if (tid < 256) sc[tid] += t;
        __syncthreads();
    }
    if (tid < 256) {
        int excl = sc[tid] - hist[tid];
        int node = b * 256 + tid;
        if (node < N_NODES) row_ptr[node] = segStart + excl;
        cur[tid] = segStart + excl;
    }
    __syncthreads();
    for (int i = tid; i < cnt; i += 1024) {
        uint2 p = seg[i];
        int pos = atomicAdd(&cur[p.x >> 16], 1);
        pairs[pos] = (p.x & 0xFFFFu) | ((unsigned int)f2bf(asfloat_u32(p.y)) << 16);
    }
}

// ---------------- GEMM, N=64(->40 valid), K=128, MFMA, fully-staged, fp8 out --------
// t3 rows fp8 64B (cols 40+ zero): 3.2MB table, halves spmm3 gather bytes.
__global__ __launch_bounds__(256) void gemm_n64(const unsigned short* __restrict__ A,
                                                const unsigned short* __restrict__ Wt2,
                                                unsigned char* __restrict__ C, int M) {
    __shared__ unsigned short As[64 * LDP2];
    __shared__ unsigned short Bs2[64 * LDP2];
    const int tid = threadIdx.x;
    const int wave = tid >> 6;
    const int lane = tid & 63;
    const int ln = lane & 15;
    const int quad = lane >> 4;
    const int row0 = blockIdx.x * 64;

#pragma unroll
    for (int i = 0; i < 4; ++i) {  // A: 64 rows x 128 = 1024 chunks of 8
        int q = tid + 256 * i;
        int r = q >> 4;
        int c = (q & 15) * 8;
        bf16x8 v;
        if (row0 + r < M) {
            v = *(const bf16x8*)(A + (size_t)(row0 + r) * 128 + c);
        } else {
#pragma unroll
            for (int j = 0; j < 8; ++j) v[j] = 0;
        }
        *(bf16x8*)&As[r * LDP2 + c] = v;
    }
#pragma unroll
    for (int i = 0; i < 4; ++i) {  // B: 64 rows x 128 = 1024 chunks of 8
        int q = tid + 256 * i;
        int r = q >> 4;
        int c = (q & 15) * 8;
        *(bf16x8*)&Bs2[r * LDP2 + c] = *(const bf16x8*)(Wt2 + (size_t)r * 128 + c);
    }
    __syncthreads();

    f32x4 acc[4];
#pragma unroll
    for (int t = 0; t < 4; ++t) acc[t] = (f32x4){0.f, 0.f, 0.f, 0.f};

#pragma unroll
    for (int kc = 0; kc < 128; kc += 32) {
        bf16x8 a = *(const bf16x8*)&As[(wave * 16 + ln) * LDP2 + kc + quad * 8];
#pragma unroll
        for (int t = 0; t < 4; ++t) {
            bf16x8 b = *(const bf16x8*)&Bs2[(t * 16 + ln) * LDP2 + kc + quad * 8];
            acc[t] = __builtin_amdgcn_mfma_f32_16x16x32_bf16(a, b, acc[t], 0, 0, 0);
        }
    }

#pragma unroll
    for (int t = 0; t < 4; ++t) {
#pragma unroll
        for (int r = 0; r < 4; ++r) {
            int row = row0 + wave * 16 + quad * 4 + r;
            if (row < M) C[(size_t)row * 64 + t * 16 + ln] = f2fp8(acc[t][r]);
        }
    }
}

// ---------------- SpMM (CSR gather, fp8 rows 128B) + bias + ReLU, feat=128 ----------
__global__ __launch_bounds__(256) void spmm_bias_relu_fp8(const unsigned char* __restrict__ t,
                                                          const int* __restrict__ row_ptr,
                                                          const unsigned int* __restrict__ pairs,
                                                          const float* __restrict__ bias,
                                                          unsigned short* __restrict__ out) {
    const int node = blockIdx.x * 4 + (threadIdx.x >> 6);
    const int lane = threadIdx.x & 63;
    const int g = lane >> 4;        // group 0..3
    const int fl = (lane & 15) * 8; // feature base: 8 fp8 = 8B owned by this lane
    const int e0 = row_ptr[node];
    const int e1 = row_ptr[node + 1];
    float acc8[8];
#pragma unroll
    for (int j = 0; j < 8; ++j) acc8[j] = 0.f;

    int e = e0;
    for (; e + 32 <= e1; e += 32) {
        unsigned int p[8];
        uint2 v[8];
#pragma unroll
        for (int i = 0; i < 8; ++i) p[i] = pairs[e + 4 * i + g];
#pragma unroll
        for (int i = 0; i < 8; ++i)
            v[i] = *(const uint2*)(t + (size_t)(p[i] & 0xFFFFu) * 128 + fl);
#pragma unroll
        for (int i = 0; i < 8; ++i) {
            float w = asfloat_u32(p[i] & 0xFFFF0000u);
            float f[8];
            dq4(v[i].x, f);
            dq4(v[i].y, f + 4);
#pragma unroll
            for (int j = 0; j < 8; ++j) acc8[j] += w * f[j];
        }
    }
    for (; e + 4 <= e1; e += 4) {
        unsigned int p = pairs[e + g];
        uint2 v = *(const uint2*)(t + (size_t)(p & 0xFFFFu) * 128 + fl);
        float w = asfloat_u32(p & 0xFFFF0000u);
        float f[8];
        dq4(v.x, f);
        dq4(v.y, f + 4);
#pragma unroll
        for (int j = 0; j < 8; ++j) acc8[j] += w * f[j];
    }
    if (g < e1 - e) {  // remainder 0..3 edges, one per group
        unsigned int p = pairs[e + g];
        uint2 v = *(const uint2*)(t + (size_t)(p & 0xFFFFu) * 128 + fl);
        float w = asfloat_u32(p & 0xFFFF0000u);
        float f[8];
        dq4(v.x, f);
        dq4(v.y, f + 4);
#pragma unroll
        for (int j = 0; j < 8; ++j) acc8[j] += w * f[j];
    }
#pragma unroll
    for (int j = 0; j < 8; ++j) {
        acc8[j] += __shfl_xor(acc8[j], 16);
        acc8[j] += __shfl_xor(acc8[j], 32);
    }
    if (g == 0) {
        float4 b0 = *(const float4*)&bias[fl];
        float4 b1 = *(const float4*)&bias[fl + 4];
        acc8[0] = fmaxf(acc8[0] + b0.x, 0.f);
        acc8[1] = fmaxf(acc8[1] + b0.y, 0.f);
        acc8[2] = fmaxf(acc8[2] + b0.z, 0.f);
        acc8[3] = fmaxf(acc8[3] + b0.w, 0.f);
        acc8[4] = fmaxf(acc8[4] + b1.x, 0.f);
        acc8[5] = fmaxf(acc8[5] + b1.y, 0.f);
        acc8[6] = fmaxf(acc8[6] + b1.z, 0.f);
        acc8[7] = fmaxf(acc8[7] + b1.w, 0.f);
        uint4 o;
        o.x = ((unsigned int)f2bf(acc8[0])) | (((unsigned int)f2bf(acc8[1])) << 16);
        o.y = ((unsigned int)f2bf(acc8[2])) | (((unsigned int)f2bf(acc8[3])) << 16);
        o.z = ((unsigned int)f2bf(acc8[4])) | (((unsigned int)f2bf(acc8[5])) << 16);
        o.w = ((unsigned int)f2bf(acc8[6])) | (((unsigned int)f2bf(acc8[7])) << 16);
        *(uint4*)(out + (size_t)node * 128 + fl) = o;
    }
}

// ---------------- SpMM feat=64pad (fp8 rows, 64B) + bias + log_softmax ----------------
__global__ __launch_bounds__(256) void spmm_logsoftmax(const unsigned char* __restrict__ t,
                                                       const int* __restrict__ row_ptr,
                                                       const unsigned int* __restrict__ pairs,
                                                       const float* __restrict__ bias,
                                                       float* __restrict__ out) {
    const int node = blockIdx.x * 4 + (threadIdx.x >> 6);
    const int lane = threadIdx.x & 63;
    const int g = lane >> 4;
    const int fe = (lane & 15) * 4;  // class base (4 fp8 = 4B)
    const int e0 = row_ptr[node];
    const int e1 = row_ptr[node + 1];
    float a0 = 0.f, a1 = 0.f, a2 = 0.f, a3 = 0.f;
    int e = e0;
    for (; e + 32 <= e1; e += 32) {
        unsigned int p[8];
        unsigned int v[8];
#pragma unroll
        for (int i = 0; i < 8; ++i) p[i] = pairs[e + 4 * i + g];
#pragma unroll
        for (int i = 0; i < 8; ++i)
            v[i] = *(const unsigned int*)(t + (size_t)(p[i] & 0xFFFFu) * 64 + fe);
#pragma unroll
        for (int i = 0; i < 8; ++i) {
            float w = asfloat_u32(p[i] & 0xFFFF0000u);
            float f[4];
            dq4(v[i], f);
            a0 += w * f[0];
            a1 += w * f[1];
            a2 += w * f[2];
            a3 += w * f[3];
        }
    }
    for (; e + 4 <= e1; e += 4) {
        unsigned int p = pairs[e + g];
        unsigned int v = *(const unsigned int*)(t + (size_t)(p & 0xFFFFu) * 64 + fe);
        float w = asfloat_u32(p & 0xFFFF0000u);
        float f[4];
        dq4(v, f);
        a0 += w * f[0]; a1 += w * f[1]; a2 += w * f[2]; a3 += w * f[3];
    }
    if (g < e1 - e) {
        unsigned int p = pairs[e + g];
        unsigned int v = *(const unsigned int*)(t + (size_t)(p & 0xFFFFu) * 64 + fe);
        float w = asfloat_u32(p & 0xFFFF0000u);
        float f[4];
        dq4(v, f);
        a0 += w * f[0]; a1 += w * f[1]; a2 += w * f[2]; a3 += w * f[3];
    }
    a0 += __shfl_xor(a0, 16); a0 += __shfl_xor(a0, 32);
    a1 += __shfl_xor(a1, 16); a1 += __shfl_xor(a1, 32);
    a2 += __shfl_xor(a2, 16); a2 += __shfl_xor(a2, 32);
    a3 += __shfl_xor(a3, 16); a3 += __shfl_xor(a3, 32);

    const bool valid = (lane & 15) < 10;  // classes fe..fe+3 < 40
    float l0 = -INFINITY, l1 = -INFINITY, l2 = -INFINITY, l3 = -INFINITY;
    if (valid) {
        float4 b = *(const float4*)&bias[fe];
        l0 = a0 + b.x; l1 = a1 + b.y; l2 = a2 + b.z; l3 = a3 + b.w;
    }
    float m = fmaxf(fmaxf(l0, l1), fmaxf(l2, l3));
#pragma unroll
    for (int off = 8; off; off >>= 1) m = fmaxf(m, __shfl_xor(m, off));
    float s = valid ? (__expf(l0 - m) + __expf(l1 - m) + __expf(l2 - m) + __expf(l3 - m)) : 0.f;
#pragma unroll
    for (int off = 8; off; off >>= 1) s += __shfl_xor(s, off);
    if (valid && g == 0) {
        float ls = __logf(s);
        float4 o;
        o.x = l0 - m - ls; o.y = l1 - m - ls; o.z = l2 - m - ls; o.w = l3 - m - ls;
        *(float4*)&out[(size_t)node * NCLASS + fe] = o;
    }
}

// ---------------- launch ----------------

extern "C" void kernel_launch(void* const* d_in, const int* in_sizes, int n_in,
                              void* d_out, int out_size, void* d_ws, size_t ws_size,
                              hipStream_t stream) {
    const float* x = (const float*)d_in[0];
    const int* edge_src = (const int*)d_in[1];
    const int* edge_dst = (const int*)d_in[2];
    const float* edge_weight = (const float*)d_in[3];
    const float* W1 = (const float*)d_in[4];
    const float* b1 = (const float*)d_in[5];
    const float* Wh = (const float*)d_in[6];
    const float* bh = (const float*)d_in[7];
    const float* W2 = (const float*)d_in[8];
    const float* b2 = (const float*)d_in[9];
    float* out = (float*)d_out;

    size_t off = 0;
    auto carve = [&](size_t bytes) {
        void* p = (char*)d_ws + off;
        off += (bytes + 511) & ~(size_t)511;
        return p;
    };
    unsigned char* tb = (unsigned char*)carve((size_t)N_NODES * 128);   // fp8 table (t / t2)
    unsigned short* hb = (unsigned short*)carve((size_t)N_NODES * 128 * 2);
    unsigned char* t3 = (unsigned char*)carve((size_t)N_NODES * 64);    // fp8 logits table
    unsigned short* Wt1 = (unsigned short*)carve((size_t)NFEAT * NHID * 2);
    unsigned short* Wth = (unsigned short*)carve((size_t)NHID * NHID * 2);
    unsigned short* Wt2 = (unsigned short*)carve((size_t)64 * NHID * 2);
    int* row_ptr = (int*)carve((size_t)(N_NODES + 4) * 4);
    int* bucketCursor = (int*)carve((size_t)NBUCKETS * 4);
    uint2* binned = (uint2*)carve((size_t)NBUCKETS * BUCKET_CAP * 8);
    unsigned int* pairs = (unsigned int*)carve((size_t)N_EDGES * 4);
    (void)ws_size; (void)n_in; (void)in_sizes; (void)out_size;

    const int prepBlocks =
        (NFEAT * NHID + NHID * NHID + 64 * NHID + NBUCKETS + 255) / 256;  // 353
    const int spmmBlocks = N_NODES / 4;            // 12500
    const int gemmBlocks = (N_NODES + 63) / 64;    // 782

    // prep (weights + cursors)
    prep_kernel<<<prepBlocks, 256, 0, stream>>>(W1, Wt1, Wh, Wth, W2, Wt2, bucketCursor);

    // GEMM1 || bin (r5-proven fusion, dst>>8 buckets)
    fused_gemm1_bin<<<GEMM1_BLOCKS + BIN_BLOCKS, 256, 0, stream>>>(
        x, Wt1, tb, edge_src, edge_dst, edge_weight, bucketCursor, binned);

    // CSR finalize (inline bucket scan)
    build_csr<<<NBUCKETS, 1024, 0, stream>>>(binned, bucketCursor, pairs, row_ptr);

    // Layer 1 aggregate (fp8 table -> bf16 hidden)
    spmm_bias_relu_fp8<<<spmmBlocks, 256, 0, stream>>>(tb, row_ptr, pairs, b1, hb);

    // Layer 2 (single-barrier fully-staged B)
    gemm64_l2<<<gemmBlocks, 256, 0, stream>>>(hb, Wth, tb);
    spmm_bias_relu_fp8<<<spmmBlocks, 256, 0, stream>>>(tb, row_ptr, pairs, bh, hb);

    // Layer 3 (MFMA, fully-staged tiles, fp8 64B logits table)
    gemm_n64<<<gemmBlocks, 256, 0, stream>>>(hb, Wt2, t3, N_NODES);
    spmm_logsoftmax<<<spmmBlocks, 256, 0, stream>>>(t3, row_ptr, pairs, b2, out);
}